// Round 8
// baseline (148.372 us; speedup 1.0000x reference)
//
#include <hip/hip_runtime.h>

// N=8, H=512, W=512, K=8, V=100000, F=200000.
// Outputs flat in d_out (f32): images (npix*4) | coords (npix*24) | normals (npix*24)
//
// R8:
//  - bf16 face table 16B/face (3.2 MB, per-XCD-L2-resident)           [R2]
//  - NT loads on streamed inputs, full-line NT stores on outputs      [R3/R6]
//  - LDS-staged lane-consecutive f32x4 stores                         [R4]
//  - NEW: 2-tile software pipeline per block (512 pixels): both tiles'
//    p2f loads + gathers issued up front; tile1's reads in flight while
//    tile0 does LDS transpose + stores. Doubles per-wave MLP to attack
//    the dependent p2f->gather HBM latency chain. Gather results kept
//    packed (u32x4 g[8], bf16 pairs) and unpacked per LDS pass to bound
//    VGPR pressure.

#define KF 8
#define ROWSTRIDE 261   // f32x4 slots per 'sub' row (bank-spread, ~2-way max)

typedef float f32x4 __attribute__((ext_vector_type(4)));
typedef int   i32x4 __attribute__((ext_vector_type(4)));
typedef unsigned int u32x4 __attribute__((ext_vector_type(4)));

__device__ __forceinline__ unsigned short f2bf(float x) {
    unsigned u = __float_as_uint(x);
    unsigned r = u + 0x7FFFu + ((u >> 16) & 1u);   // round-to-nearest-even
    return (unsigned short)(r >> 16);
}
__device__ __forceinline__ float bf2f(unsigned int hi16) {
    return __uint_as_float(hi16 << 16);
}

// c[j] (j=0..23): k=j/3; r=j%3: {lo(g[k].x), hi(g[k].x), lo(g[k].y)}
__device__ __forceinline__ float c_elem(const u32x4* g, int j) {
    int k = j / 3, r = j - 3 * k;
    unsigned v = (r == 0) ? (g[k].x & 0xFFFFu)
               : (r == 1) ? (g[k].x >> 16)
                          : (g[k].y & 0xFFFFu);
    return bf2f(v);
}
// n[j]: {hi(g[k].y), lo(g[k].z), hi(g[k].z)}
__device__ __forceinline__ float n_elem(const u32x4* g, int j) {
    int k = j / 3, r = j - 3 * k;
    unsigned v = (r == 0) ? (g[k].y >> 16)
               : (r == 1) ? (g[k].z & 0xFFFFu)
                          : (g[k].z >> 16);
    return bf2f(v);
}

// ---------------------------------------------------------------------------
// Kernel 1: bf16 face table, 16 B/face: {cx,cy | cz,nx | ny,nz | 0}
// Normal (cached) stores: we WANT the table resident.
// ---------------------------------------------------------------------------
__global__ void build_face_table_kernel(const float* __restrict__ verts,
                                        const int* __restrict__ faces,
                                        const float* __restrict__ fnorm,
                                        u32x4* __restrict__ table,
                                        int F) {
    int f = blockIdx.x * blockDim.x + threadIdx.x;
    if (f >= F) return;
    int i0 = faces[3 * f + 0];
    int i1 = faces[3 * f + 1];
    int i2 = faces[3 * f + 2];
    const float inv3 = 1.0f / 3.0f;
    float cx = (verts[3 * i0 + 0] + verts[3 * i1 + 0] + verts[3 * i2 + 0]) * inv3;
    float cy = (verts[3 * i0 + 1] + verts[3 * i1 + 1] + verts[3 * i2 + 1]) * inv3;
    float cz = (verts[3 * i0 + 2] + verts[3 * i1 + 2] + verts[3 * i2 + 2]) * inv3;
    float nx = fnorm[3 * f + 0];
    float ny = fnorm[3 * f + 1];
    float nz = fnorm[3 * f + 2];
    u32x4 t;
    t.x = (unsigned)f2bf(cx) | ((unsigned)f2bf(cy) << 16);
    t.y = (unsigned)f2bf(cz) | ((unsigned)f2bf(nx) << 16);
    t.z = (unsigned)f2bf(ny) | ((unsigned)f2bf(nz) << 16);
    t.w = 0u;
    table[f] = t;
}

// ---------------------------------------------------------------------------
// Kernel 2 (fast path, npix % 512 == 0): 2-tile pipelined shade.
// Block = 256 threads, covers 512 pixels (tiles T0, T1).
// ---------------------------------------------------------------------------
__global__ void __launch_bounds__(256) shade_lds2_kernel(
    const int* __restrict__ p2f,
    const float* __restrict__ texels,
    const u32x4* __restrict__ table,
    f32x4* __restrict__ images,    // npix
    f32x4* __restrict__ coords,    // npix*6
    f32x4* __restrict__ normals,   // npix*6
    int npix) {
    __shared__ f32x4 lds4[6 * ROWSTRIDE];
    const int tid = threadIdx.x;
    const int base = blockIdx.x * 512;
    const int p0 = base + tid;
    const int p1 = base + 256 + tid;

    // ---- phase 1: both tiles' p2f loads in flight ----
    const i32x4* pf0 = (const i32x4*)(p2f + (size_t)p0 * KF);
    const i32x4* pf1 = (const i32x4*)(p2f + (size_t)p1 * KF);
    i32x4 fa0 = __builtin_nontemporal_load(&pf0[0]);
    i32x4 fb0 = __builtin_nontemporal_load(&pf0[1]);
    i32x4 fa1 = __builtin_nontemporal_load(&pf1[0]);
    i32x4 fb1 = __builtin_nontemporal_load(&pf1[1]);

    // ---- phase 2: T0 gathers + texel ----
    int fid0[KF] = {fa0.x, fa0.y, fa0.z, fa0.w, fb0.x, fb0.y, fb0.z, fb0.w};
    bool fg0 = fa0.x >= 0;
    f32x4 tex0;
    if (fg0) tex0 = __builtin_nontemporal_load((const f32x4*)(texels + (size_t)p0 * (KF * 3)));
    u32x4 g0[KF];
#pragma unroll
    for (int k = 0; k < KF; ++k) {
        u32x4 t = {0u, 0u, 0u, 0u};
        if (fid0[k] >= 0) t = table[fid0[k]];   // exec-masked gather
        g0[k] = t;
    }

    // ---- phase 3: T1 gathers + texel (in flight during T0's store phase) ----
    int fid1[KF] = {fa1.x, fa1.y, fa1.z, fa1.w, fb1.x, fb1.y, fb1.z, fb1.w};
    bool fg1 = fa1.x >= 0;
    f32x4 tex1;
    if (fg1) tex1 = __builtin_nontemporal_load((const f32x4*)(texels + (size_t)p1 * (KF * 3)));
    u32x4 g1[KF];
#pragma unroll
    for (int k = 0; k < KF; ++k) {
        u32x4 t = {0u, 0u, 0u, 0u};
        if (fid1[k] >= 0) t = table[fid1[k]];
        g1[k] = t;
    }

    const size_t obase = (size_t)base * 6;      // block's f32x4 slot base

    // ---- phase 4: T0 outputs ----
    {
        f32x4 img;
        if (fg0) { img.x = tex0.x; img.y = tex0.y; img.z = tex0.z; img.w = 1.0f; }
        else     { img.x = 1.0f;   img.y = 1.0f;   img.z = 1.0f;   img.w = 0.0f; }
        __builtin_nontemporal_store(img, &images[p0]);
    }
#pragma unroll
    for (int q = 0; q < 6; ++q) {
        f32x4 v = {c_elem(g0, 4 * q + 0), c_elem(g0, 4 * q + 1),
                   c_elem(g0, 4 * q + 2), c_elem(g0, 4 * q + 3)};
        lds4[q * ROWSTRIDE + tid] = v;
    }
    __syncthreads();
#pragma unroll
    for (int j = 0; j < 6; ++j) {
        int idx = tid + 256 * j;
        int pix = idx / 6;
        int sub = idx - pix * 6;
        f32x4 v = lds4[sub * ROWSTRIDE + pix];
        __builtin_nontemporal_store(v, &coords[obase + idx]);
    }
    __syncthreads();
#pragma unroll
    for (int q = 0; q < 6; ++q) {
        f32x4 v = {n_elem(g0, 4 * q + 0), n_elem(g0, 4 * q + 1),
                   n_elem(g0, 4 * q + 2), n_elem(g0, 4 * q + 3)};
        lds4[q * ROWSTRIDE + tid] = v;
    }
    __syncthreads();
#pragma unroll
    for (int j = 0; j < 6; ++j) {
        int idx = tid + 256 * j;
        int pix = idx / 6;
        int sub = idx - pix * 6;
        f32x4 v = lds4[sub * ROWSTRIDE + pix];
        __builtin_nontemporal_store(v, &normals[obase + idx]);
    }
    __syncthreads();

    // ---- phase 5: T1 outputs ----
    {
        f32x4 img;
        if (fg1) { img.x = tex1.x; img.y = tex1.y; img.z = tex1.z; img.w = 1.0f; }
        else     { img.x = 1.0f;   img.y = 1.0f;   img.z = 1.0f;   img.w = 0.0f; }
        __builtin_nontemporal_store(img, &images[p1]);
    }
#pragma unroll
    for (int q = 0; q < 6; ++q) {
        f32x4 v = {c_elem(g1, 4 * q + 0), c_elem(g1, 4 * q + 1),
                   c_elem(g1, 4 * q + 2), c_elem(g1, 4 * q + 3)};
        lds4[q * ROWSTRIDE + tid] = v;
    }
    __syncthreads();
#pragma unroll
    for (int j = 0; j < 6; ++j) {
        int idx = tid + 256 * j;
        int pix = idx / 6;
        int sub = idx - pix * 6;
        f32x4 v = lds4[sub * ROWSTRIDE + pix];
        __builtin_nontemporal_store(v, &coords[obase + 1536 + idx]);
    }
    __syncthreads();
#pragma unroll
    for (int q = 0; q < 6; ++q) {
        f32x4 v = {n_elem(g1, 4 * q + 0), n_elem(g1, 4 * q + 1),
                   n_elem(g1, 4 * q + 2), n_elem(g1, 4 * q + 3)};
        lds4[q * ROWSTRIDE + tid] = v;
    }
    __syncthreads();
#pragma unroll
    for (int j = 0; j < 6; ++j) {
        int idx = tid + 256 * j;
        int pix = idx / 6;
        int sub = idx - pix * 6;
        f32x4 v = lds4[sub * ROWSTRIDE + pix];
        __builtin_nontemporal_store(v, &normals[obase + 1536 + idx]);
    }
}

// ---------------------------------------------------------------------------
// Kernel 2b (npix % 256 == 0 but not % 512): R7's single-tile version.
// ---------------------------------------------------------------------------
__global__ void __launch_bounds__(256) shade_lds_kernel(
    const int* __restrict__ p2f,
    const float* __restrict__ texels,
    const u32x4* __restrict__ table,
    f32x4* __restrict__ images,
    f32x4* __restrict__ coords,
    f32x4* __restrict__ normals,
    int npix) {
    __shared__ f32x4 lds4[6 * ROWSTRIDE];
    const int tid = threadIdx.x;
    const int p = blockIdx.x * 256 + tid;

    const i32x4* pf = (const i32x4*)(p2f + (size_t)p * KF);
    i32x4 fa = __builtin_nontemporal_load(&pf[0]);
    i32x4 fb = __builtin_nontemporal_load(&pf[1]);
    int fid[KF] = {fa.x, fa.y, fa.z, fa.w, fb.x, fb.y, fb.z, fb.w};

    bool fg = fa.x >= 0;
    f32x4 tex;
    if (fg) tex = __builtin_nontemporal_load((const f32x4*)(texels + (size_t)p * (KF * 3)));

    u32x4 g[KF];
#pragma unroll
    for (int k = 0; k < KF; ++k) {
        u32x4 t = {0u, 0u, 0u, 0u};
        if (fid[k] >= 0) t = table[fid[k]];
        g[k] = t;
    }

    const size_t gbase = (size_t)blockIdx.x * (256 * 6);

#pragma unroll
    for (int q = 0; q < 6; ++q) {
        f32x4 v = {c_elem(g, 4 * q + 0), c_elem(g, 4 * q + 1),
                   c_elem(g, 4 * q + 2), c_elem(g, 4 * q + 3)};
        lds4[q * ROWSTRIDE + tid] = v;
    }
    f32x4 img;
    if (fg) { img.x = tex.x; img.y = tex.y; img.z = tex.z; img.w = 1.0f; }
    else    { img.x = 1.0f;  img.y = 1.0f;  img.z = 1.0f;  img.w = 0.0f; }
    __builtin_nontemporal_store(img, &images[p]);
    __syncthreads();
#pragma unroll
    for (int j = 0; j < 6; ++j) {
        int idx = tid + 256 * j;
        int pix = idx / 6;
        int sub = idx - pix * 6;
        f32x4 v = lds4[sub * ROWSTRIDE + pix];
        __builtin_nontemporal_store(v, &coords[gbase + idx]);
    }
    __syncthreads();
#pragma unroll
    for (int q = 0; q < 6; ++q) {
        f32x4 v = {n_elem(g, 4 * q + 0), n_elem(g, 4 * q + 1),
                   n_elem(g, 4 * q + 2), n_elem(g, 4 * q + 3)};
        lds4[q * ROWSTRIDE + tid] = v;
    }
    __syncthreads();
#pragma unroll
    for (int j = 0; j < 6; ++j) {
        int idx = tid + 256 * j;
        int pix = idx / 6;
        int sub = idx - pix * 6;
        f32x4 v = lds4[sub * ROWSTRIDE + pix];
        __builtin_nontemporal_store(v, &normals[gbase + idx]);
    }
}

// ---------------------------------------------------------------------------
// Fallback: inline gather, direct stores (exact f32).
// ---------------------------------------------------------------------------
__global__ void __launch_bounds__(256) shade_inline_kernel(
    const int* __restrict__ p2f,
    const float* __restrict__ texels,
    const float* __restrict__ verts,
    const int* __restrict__ faces,
    const float* __restrict__ fnorm,
    f32x4* __restrict__ images,
    f32x4* __restrict__ coords,
    f32x4* __restrict__ normals,
    int npix) {
    int p = blockIdx.x * blockDim.x + threadIdx.x;
    if (p >= npix) return;

    const i32x4* pf = (const i32x4*)(p2f + (size_t)p * KF);
    i32x4 fa = pf[0];
    i32x4 fb = pf[1];
    int fid[KF] = {fa.x, fa.y, fa.z, fa.w, fb.x, fb.y, fb.z, fb.w};

    float c[24], n[24];
#pragma unroll
    for (int k = 0; k < KF; ++k) {
        int f = fid[k];
        float cx = 0.f, cy = 0.f, cz = 0.f, nx = 0.f, ny = 0.f, nz = 0.f;
        if (f >= 0) {
            int i0 = faces[3 * f + 0];
            int i1 = faces[3 * f + 1];
            int i2 = faces[3 * f + 2];
            const float inv3 = 1.0f / 3.0f;
            cx = (verts[3 * i0 + 0] + verts[3 * i1 + 0] + verts[3 * i2 + 0]) * inv3;
            cy = (verts[3 * i0 + 1] + verts[3 * i1 + 1] + verts[3 * i2 + 1]) * inv3;
            cz = (verts[3 * i0 + 2] + verts[3 * i1 + 2] + verts[3 * i2 + 2]) * inv3;
            nx = fnorm[3 * f + 0];
            ny = fnorm[3 * f + 1];
            nz = fnorm[3 * f + 2];
        }
        c[3 * k + 0] = cx; c[3 * k + 1] = cy; c[3 * k + 2] = cz;
        n[3 * k + 0] = nx; n[3 * k + 1] = ny; n[3 * k + 2] = nz;
    }

    size_t ob = (size_t)p * 6;
#pragma unroll
    for (int q = 0; q < 6; ++q) {
        f32x4 v = {c[4 * q + 0], c[4 * q + 1], c[4 * q + 2], c[4 * q + 3]};
        coords[ob + q] = v;
    }
#pragma unroll
    for (int q = 0; q < 6; ++q) {
        f32x4 v = {n[4 * q + 0], n[4 * q + 1], n[4 * q + 2], n[4 * q + 3]};
        normals[ob + q] = v;
    }

    f32x4 img;
    if (fid[0] >= 0) {
        f32x4 t = *(const f32x4*)(texels + (size_t)p * (KF * 3));
        img.x = t.x; img.y = t.y; img.z = t.z; img.w = 1.0f;
    } else {
        img.x = 1.0f; img.y = 1.0f; img.z = 1.0f; img.w = 0.0f;
    }
    images[p] = img;
}

extern "C" void kernel_launch(void* const* d_in, const int* in_sizes, int n_in,
                              void* d_out, int out_size, void* d_ws, size_t ws_size,
                              hipStream_t stream) {
    const float* verts = (const float*)d_in[0];
    const int* faces = (const int*)d_in[1];
    const float* fnorm = (const float*)d_in[2];
    const int* p2f = (const int*)d_in[3];
    const float* texels = (const float*)d_in[4];

    const int F = in_sizes[1] / 3;
    const int npix = in_sizes[3] / KF;   // N*H*W

    float* out = (float*)d_out;
    f32x4* images = (f32x4*)out;
    f32x4* coords = (f32x4*)(out + (size_t)npix * 4);
    f32x4* normals = (f32x4*)(out + (size_t)npix * 4 + (size_t)npix * 24);

    const size_t ws_needed = (size_t)F * sizeof(u32x4);   // 3.2 MB

    dim3 blk(256);

    if (ws_size >= ws_needed && (npix % 256) == 0) {
        u32x4* table = (u32x4*)d_ws;
        dim3 grid_f((F + 255) / 256);
        build_face_table_kernel<<<grid_f, blk, 0, stream>>>(verts, faces, fnorm, table, F);
        if ((npix % 512) == 0) {
            dim3 grid_pix(npix / 512);
            shade_lds2_kernel<<<grid_pix, blk, 0, stream>>>(p2f, texels, table,
                                                            images, coords, normals, npix);
        } else {
            dim3 grid_pix(npix / 256);
            shade_lds_kernel<<<grid_pix, blk, 0, stream>>>(p2f, texels, table,
                                                           images, coords, normals, npix);
        }
    } else {
        dim3 grid_pix((npix + 255) / 256);
        shade_inline_kernel<<<grid_pix, blk, 0, stream>>>(p2f, texels, verts, faces, fnorm,
                                                          images, coords, normals, npix);
    }
}